// Round 6
// baseline (304.309 us; speedup 1.0000x reference)
//
#include <hip/hip_runtime.h>
#include <cstdint>
#include <cstddef>

#define B_    8
#define N_    2048
#define FIN   128
#define FOUT  64
#define ALPHA 0.2f
#define NEG_BIG -9.0e15f

typedef __attribute__((ext_vector_type(8))) _Float16 half8;
typedef __attribute__((ext_vector_type(4))) float float4v;

// ---------------------------------------------------------------------------
// Kernel 0: pack adj (134 MB int32) -> bitmask (4.2 MB), pure streamer.
// Barrier-free, no phase lockstep -> HBM runs at duty ~1 (the R1-R5 k2s all
// idled HBM at ~15% because barriers gated load-issue windows).
// Lane l packs j-range [l*32, l*32+32) of its row into one dword (bit j&31);
// write is 64 contiguous dwords/wave = perfectly coalesced.
// ---------------------------------------------------------------------------
__global__ __launch_bounds__(256, 8) void k0_pack(
    const int* __restrict__ adj, unsigned int* __restrict__ bm)
{
    int t = threadIdx.x, lane = t & 63, w = t >> 6;
    int rowBase = blockIdx.x * 8 + w * 2;          // 2048 blocks, 2 rows/wave
    #pragma unroll
    for (int rr = 0; rr < 2; ++rr) {
        int row = rowBase + rr;
        const int* ap = adj + (size_t)row * N_ + lane * 32;
        unsigned int m = 0;
        #pragma unroll
        for (int q = 0; q < 8; ++q) {              // 8 int4 = 32 ints per lane
            int4 a = *(const int4*)(ap + q * 4);
            m |= (a.x > 0 ? 1u : 0u) << (q * 4 + 0);
            m |= (a.y > 0 ? 1u : 0u) << (q * 4 + 1);
            m |= (a.z > 0 ? 1u : 0u) << (q * 4 + 2);
            m |= (a.w > 0 ? 1u : 0u) << (q * 4 + 3);
        }
        bm[(size_t)row * 64 + lane] = m;
    }
}

// ---------------------------------------------------------------------------
// Kernel 1: wh = x @ W  (fp32 accumulate), store whT[b][f][j] as fp16,
//           s1 = wh@a1, s2 = wh@a2 (fp32).
// ---------------------------------------------------------------------------
__global__ __launch_bounds__(256, 4) void k1_wh(
    const float* __restrict__ x, const float* __restrict__ W,
    const float* __restrict__ w2, _Float16* __restrict__ whT,
    float* __restrict__ s1, float* __restrict__ s2)
{
    int t = threadIdx.x, lane = t & 63, w = t >> 6;
    float a1 = w2[lane], a2 = w2[FOUT + lane];
    int rowBase = blockIdx.x * 32 + w * 8;   // 32 rows/block, 8 rows/wave
    for (int rr = 0; rr < 8; ++rr) {
        int row = __builtin_amdgcn_readfirstlane(rowBase + rr);  // wave-uniform
        const float* xr = x + (size_t)row * FIN;
        float acc = 0.f;
        #pragma unroll
        for (int k = 0; k < FIN; ++k)
            acc = fmaf(xr[k], W[k * FOUT + lane], acc);
        int b = row >> 11, j = row & (N_ - 1);
        whT[((size_t)b * FOUT + lane) * N_ + j] = (_Float16)acc;
        float p1 = acc * a1, p2 = acc * a2;
        #pragma unroll
        for (int m = 32; m >= 1; m >>= 1) {
            p1 += __shfl_xor(p1, m);
            p2 += __shfl_xor(p2, m);
        }
        if (lane == 0) { s1[row] = p1; s2[row] = p2; }
    }
}

// ---------------------------------------------------------------------------
// Kernel 1b: smax[b] = max_j s2[b][j]  (one block per batch, ~1 us total).
// Removes the per-block s2max preamble + barrier from k2.
// ---------------------------------------------------------------------------
__global__ void k1b_smax(const float* __restrict__ s2, float* __restrict__ smax)
{
    __shared__ float red[4];
    int t = threadIdx.x, lane = t & 63, w = t >> 6;
    const float4* p = (const float4*)(s2 + (size_t)blockIdx.x * N_);
    float4 a = p[t], c = p[t + 256];
    float m = fmaxf(fmaxf(fmaxf(a.x, a.y), fmaxf(a.z, a.w)),
                    fmaxf(fmaxf(c.x, c.y), fmaxf(c.z, c.w)));
    #pragma unroll
    for (int s = 32; s >= 1; s >>= 1) m = fmaxf(m, __shfl_xor(m, s));
    if (lane == 0) red[w] = m;
    __syncthreads();
    if (t == 0)
        smax[blockIdx.x] = fmaxf(fmaxf(red[0], red[1]), fmaxf(red[2], red[3]));
}

// ---------------------------------------------------------------------------
// Kernel 2: masked softmax + PV via MFMA — R2 structure (measured best),
// adj replaced by L2-resident bitmask (4 MB total; 4 KB per block).
// Block = 16 rows x full j, 4 waves; p-phase wave w owns rows w*4..+3,
// MFMA phase wave w owns features w*16..+15; single pT buffer.
// m^ = leaky(s1_i + smax_b) >= true row max -> partials merge w/o rescale;
// masked -> exp(-76) ~ 0 (reproduces uniform softmax for all-masked rows).
// A-frag: row=lane&15, k=quad*8+e. C/D: col=lane&15, row=quad*4+reg.
// B-frag loads stay interleaved in the MFMA loop (R5 lesson: batching them
// ahead of critical loads inverts the FIFO vmcnt queue).
// ---------------------------------------------------------------------------
__global__ __launch_bounds__(256, 6) void k2_attn(
    const unsigned int* __restrict__ bm, const _Float16* __restrict__ whT,
    const float* __restrict__ s1, const float* __restrict__ s2,
    const float* __restrict__ smax, float* __restrict__ out)
{
    __shared__ __attribute__((aligned(16))) _Float16 pT[16][520];
    __shared__ float lL[16];

    int t = threadIdx.x, lane = t & 63, w = t >> 6;
    int b = blockIdx.x >> 7;
    int i0 = (blockIdx.x & 127) << 4;

    float s2max = smax[b];                 // scalar, L2-hot

    int l15 = lane & 15, quad = lane >> 4;
    int f0 = w * 16;

    float s1r[4], negmh[4], lacc[4];
    #pragma unroll
    for (int rr = 0; rr < 4; ++rr) {
        float sv = s1[(size_t)b * N_ + i0 + w * 4 + rr];  // wave-uniform
        float mh = sv + s2max;
        mh = fmaxf(mh, ALPHA * mh);        // leaky(s1_i + s2max) >= row max
        s1r[rr] = sv;
        negmh[rr] = -mh;
        lacc[rr] = 0.f;
    }

    // bitmask: row dword layout — lane needs dword (lane>>2) within each
    // 512-j chunk (16 dwords), then byte (lane&3), bit e.
    const unsigned int* bmB =
        bm + ((size_t)b * N_ + i0 + w * 4) * 64 + (lane >> 2);
    int bsh = (lane & 3) * 8;
    const float*    s2B = s2 + (size_t)b * N_ + lane * 8;
    const _Float16* wB  = whT + ((size_t)b * FOUT + f0 + l15) * N_ + quad * 8;

    float4v acc = {0, 0, 0, 0};

    #pragma unroll
    for (int c = 0; c < 4; ++c) {
        const int jc = c * 512;

        const float* s2c = s2B + jc;
        float4 sa = *(const float4*)s2c;
        float4 sb = *(const float4*)(s2c + 4);
        float ss[8] = {sa.x, sa.y, sa.z, sa.w, sb.x, sb.y, sb.z, sb.w};

        #pragma unroll
        for (int rr = 0; rr < 4; ++rr) {
            unsigned int by = (bmB[(size_t)rr * 64 + c * 16] >> bsh) & 0xffu;
            half8 pf;
            float ls = 0.f;
            #pragma unroll
            for (int e = 0; e < 8; ++e) {
                float v = s1r[rr] + ss[e];
                v = fmaxf(v, ALPHA * v);                 // leaky relu
                v = (by & (1u << e)) ? v : NEG_BIG;      // mask from bit
                float tt = fmaxf(v + negmh[rr], -76.f);  // masked -> exp ~ 0
                float p = __expf(tt);                    // p in (0,1]
                ls += p;
                pf[e] = (_Float16)p;
            }
            lacc[rr] += ls;
            *(half8*)&pT[w * 4 + rr][lane * 8] = pf;     // contiguous b128
        }

        if (c == 3) {
            // final row-sum reduction before the barrier that publishes pT
            #pragma unroll
            for (int rr = 0; rr < 4; ++rr) {
                float v = lacc[rr];
                #pragma unroll
                for (int m = 32; m >= 1; m >>= 1) v += __shfl_xor(v, m);
                if (lane == 0) lL[w * 4 + rr] = v;
            }
        }
        __syncthreads();

        // MFMA phase: wave w's 16-feature group, K-chunk of 512.
        const _Float16* wp = wB + jc;
        #pragma unroll
        for (int kk = 0; kk < 16; ++kk) {
            half8 af = *(const half8*)&pT[l15][kk * 32 + quad * 8];
            half8 bf = *(const half8*)(wp + kk * 32);
            acc = __builtin_amdgcn_mfma_f32_16x16x32_f16(af, bf, acc, 0, 0, 0);
        }
        __syncthreads();
    }

    // epilogue: normalize, ELU, store. D: row=quad*4+reg, col=f0+l15
    #pragma unroll
    for (int reg = 0; reg < 4; ++reg) {
        int row = quad * 4 + reg;
        float val = acc[reg] / lL[row];
        val = (val > 0.f) ? val : (__expf(val) - 1.f);   // ELU
        out[((size_t)b * N_ + i0 + row) * FOUT + f0 + l15] = val;
    }
}

// ---------------------------------------------------------------------------
extern "C" void kernel_launch(void* const* d_in, const int* in_sizes, int n_in,
                              void* d_out, int out_size, void* d_ws, size_t ws_size,
                              hipStream_t stream) {
    const float* x   = (const float*)d_in[0];
    const int*   adj = (const int*)d_in[1];
    const float* W   = (const float*)d_in[2];
    const float* w2  = (const float*)d_in[3];
    float* out = (float*)d_out;

    char* ws = (char*)d_ws;
    _Float16*     whT  = (_Float16*)ws;                      ws += (size_t)B_ * FOUT * N_ * 2;  // 2 MiB
    float*        s1   = (float*)ws;                         ws += (size_t)B_ * N_ * 4;         // 64 KiB
    float*        s2   = (float*)ws;                         ws += (size_t)B_ * N_ * 4;         // 64 KiB
    float*        smax = (float*)ws;                         ws += 256;
    unsigned int* bmsk = (unsigned int*)ws;                  // 4 MiB

    k0_pack<<<(B_ * N_) / 8, 256, 0, stream>>>(adj, bmsk);
    k1_wh<<<(B_ * N_) / 32, 256, 0, stream>>>(x, W, w2, whT, s1, s2);
    k1b_smax<<<B_, 256, 0, stream>>>(s2, smax);
    k2_attn<<<(B_ * N_) / 16, 256, 0, stream>>>(bmsk, whT, s1, s2, smax, out);
}

// Round 7
// 274.312 us; speedup vs baseline: 1.1094x; 1.1094x over previous
//
#include <hip/hip_runtime.h>
#include <cstdint>
#include <cstddef>

#define B_    8
#define N_    2048
#define FIN   128
#define FOUT  64
#define ALPHA 0.2f
#define NEG_BIG -9.0e15f

typedef __attribute__((ext_vector_type(8))) _Float16 half8;
typedef __attribute__((ext_vector_type(4))) float float4v;

// ---------------------------------------------------------------------------
// Kernel 1: wh = x @ W  (fp32 accumulate), store whT[b][f][j] as fp16,
//           s1 = wh@a1, s2 = wh@a2 (fp32).
// ---------------------------------------------------------------------------
__global__ __launch_bounds__(256, 4) void k1_wh(
    const float* __restrict__ x, const float* __restrict__ W,
    const float* __restrict__ w2, _Float16* __restrict__ whT,
    float* __restrict__ s1, float* __restrict__ s2)
{
    int t = threadIdx.x, lane = t & 63, w = t >> 6;
    float a1 = w2[lane], a2 = w2[FOUT + lane];
    int rowBase = blockIdx.x * 32 + w * 8;   // 32 rows/block, 8 rows/wave
    for (int rr = 0; rr < 8; ++rr) {
        int row = __builtin_amdgcn_readfirstlane(rowBase + rr);  // wave-uniform
        const float* xr = x + (size_t)row * FIN;
        float acc = 0.f;
        #pragma unroll
        for (int k = 0; k < FIN; ++k)
            acc = fmaf(xr[k], W[k * FOUT + lane], acc);
        int b = row >> 11, j = row & (N_ - 1);
        whT[((size_t)b * FOUT + lane) * N_ + j] = (_Float16)acc;
        float p1 = acc * a1, p2 = acc * a2;
        #pragma unroll
        for (int m = 32; m >= 1; m >>= 1) {
            p1 += __shfl_xor(p1, m);
            p2 += __shfl_xor(p2, m);
        }
        if (lane == 0) { s1[row] = p1; s2[row] = p2; }
    }
}

// ---------------------------------------------------------------------------
// Kernel 2: masked softmax + PV via MFMA — R2 structure (measured best:
// total 254.3us) + loop-carried REGISTER prefetch of next chunk's adj/s2.
// Block = 16 rows x full j, 4 waves. p-phase: wave w owns rows w*4..+3,
// adj reads fully coalesced (lane*32B); p (fp16) -> LDS pT[16][520].
// MFMA phase: wave w owns features w*16..+15, A from LDS, B from L2 whT.
// PIPELINE (the one change vs R2): chunk c+1's adj (8 int4) + s2 (2 float4)
// are issued between the p-publish barrier and the MFMA loop of chunk c,
// carried in registers across the barrier, consumed next p-phase. R2's
// VGPR=64 proved the compiler never did this on its own; this forces one
// HBM-latency exposure per chunk to overlap MFMA+ds_read+barrier instead
// of serializing. adj prefetch issues BEFORE B-frag loads (FIFO vmcnt:
// critical loads first — R5 lesson).
// m^ = leaky(s1_i + s2max_b) >= true row max -> no online rescaling;
// masked entries floor at exp(-76)~0 (reproduces uniform softmax for
// all-masked rows). A-frag: row=lane&15, k=quad*8+e. C/D: col=lane&15,
// row=quad*4+reg. pT stride 520 halfs -> A-reads 8 lanes per 4-bank group
// (structural minimum, conflict-free).
// ---------------------------------------------------------------------------
__global__ __launch_bounds__(256, 4) void k2_attn(
    const int* __restrict__ adj, const _Float16* __restrict__ whT,
    const float* __restrict__ s1, const float* __restrict__ s2,
    float* __restrict__ out)
{
    __shared__ __attribute__((aligned(16))) _Float16 pT[16][520];
    __shared__ float lL[16];
    __shared__ float smaxL[4];

    int t = threadIdx.x, lane = t & 63, w = t >> 6;
    int b = blockIdx.x >> 7;
    int i0 = (blockIdx.x & 127) << 4;

    // --- exact S2MAX over batch b (8 KB, L2-hot) ---
    const float4* s2v = (const float4*)(s2 + (size_t)b * N_);
    float4 ua = s2v[t], ub = s2v[t + 256];
    float vm = fmaxf(fmaxf(fmaxf(ua.x, ua.y), fmaxf(ua.z, ua.w)),
                     fmaxf(fmaxf(ub.x, ub.y), fmaxf(ub.z, ub.w)));
    #pragma unroll
    for (int m = 32; m >= 1; m >>= 1) vm = fmaxf(vm, __shfl_xor(vm, m));
    if (lane == 0) smaxL[w] = vm;
    __syncthreads();
    float s2max = fmaxf(fmaxf(smaxL[0], smaxL[1]), fmaxf(smaxL[2], smaxL[3]));

    int l15 = lane & 15, quad = lane >> 4;
    int f0 = w * 16;

    float s1r[4], negmh[4], lacc[4];
    #pragma unroll
    for (int rr = 0; rr < 4; ++rr) {
        float sv = s1[(size_t)b * N_ + i0 + w * 4 + rr];  // wave-uniform
        float mh = sv + s2max;
        mh = fmaxf(mh, ALPHA * mh);        // leaky(s1_i + s2max) >= row max
        s1r[rr] = sv;
        negmh[rr] = -mh;
        lacc[rr] = 0.f;
    }

    const int*      adjB = adj + ((size_t)b * N_ + i0 + w * 4) * N_ + lane * 8;
    const float*    s2B  = s2 + (size_t)b * N_ + lane * 8;
    const _Float16* wB   = whT + ((size_t)b * FOUT + f0 + l15) * N_ + quad * 8;

    float4v acc = {0, 0, 0, 0};

    // loop-carried prefetch registers
    int4   aj[4][2];
    float4 sa, sb;

    // prologue: chunk 0 loads
    #pragma unroll
    for (int rr = 0; rr < 4; ++rr) {
        aj[rr][0] = *(const int4*)(adjB + (size_t)rr * N_);
        aj[rr][1] = *(const int4*)(adjB + (size_t)rr * N_ + 4);
    }
    sa = *(const float4*)s2B;
    sb = *(const float4*)(s2B + 4);

    #pragma unroll
    for (int c = 0; c < 4; ++c) {
        const int jc = c * 512;

        // ---- p-phase: consume prefetched regs ----
        float ss[8] = {sa.x, sa.y, sa.z, sa.w, sb.x, sb.y, sb.z, sb.w};
        #pragma unroll
        for (int rr = 0; rr < 4; ++rr) {
            int aa[8] = {aj[rr][0].x, aj[rr][0].y, aj[rr][0].z, aj[rr][0].w,
                         aj[rr][1].x, aj[rr][1].y, aj[rr][1].z, aj[rr][1].w};
            half8 pf;
            float ls = 0.f;
            #pragma unroll
            for (int e = 0; e < 8; ++e) {
                float v = s1r[rr] + ss[e];
                v = fmaxf(v, ALPHA * v);                 // leaky relu
                v = (aa[e] > 0) ? v : NEG_BIG;           // mask
                float tt = fmaxf(v + negmh[rr], -76.f);  // masked -> exp ~ 0
                float p = __expf(tt);                    // p in (0,1]
                ls += p;
                pf[e] = (_Float16)p;
            }
            lacc[rr] += ls;
            *(half8*)&pT[w * 4 + rr][lane * 8] = pf;     // contiguous b128
        }

        if (c == 3) {
            // final row-sum reduction before the barrier that publishes pT
            #pragma unroll
            for (int rr = 0; rr < 4; ++rr) {
                float v = lacc[rr];
                #pragma unroll
                for (int m = 32; m >= 1; m >>= 1) v += __shfl_xor(v, m);
                if (lane == 0) lL[w * 4 + rr] = v;
            }
        }
        __syncthreads();

        // ---- prefetch chunk c+1 (critical loads first: FIFO vmcnt) ----
        if (c < 3) {
            const int jn = jc + 512;
            #pragma unroll
            for (int rr = 0; rr < 4; ++rr) {
                aj[rr][0] = *(const int4*)(adjB + (size_t)rr * N_ + jn);
                aj[rr][1] = *(const int4*)(adjB + (size_t)rr * N_ + jn + 4);
            }
            sa = *(const float4*)(s2B + jn);
            sb = *(const float4*)(s2B + jn + 4);
        }

        // ---- MFMA phase: wave w's 16-feature group, K-chunk of 512 ----
        const _Float16* wp = wB + jc;
        #pragma unroll
        for (int kk = 0; kk < 16; ++kk) {
            half8 af = *(const half8*)&pT[l15][kk * 32 + quad * 8];
            half8 bf = *(const half8*)(wp + kk * 32);
            acc = __builtin_amdgcn_mfma_f32_16x16x32_f16(af, bf, acc, 0, 0, 0);
        }
        __syncthreads();
    }

    // epilogue: normalize, ELU, store. D: row=quad*4+reg, col=f0+l15
    #pragma unroll
    for (int reg = 0; reg < 4; ++reg) {
        int row = quad * 4 + reg;
        float val = acc[reg] / lL[row];
        val = (val > 0.f) ? val : (__expf(val) - 1.f);   // ELU
        out[((size_t)b * N_ + i0 + row) * FOUT + f0 + l15] = val;
    }
}

// ---------------------------------------------------------------------------
extern "C" void kernel_launch(void* const* d_in, const int* in_sizes, int n_in,
                              void* d_out, int out_size, void* d_ws, size_t ws_size,
                              hipStream_t stream) {
    const float* x   = (const float*)d_in[0];
    const int*   adj = (const int*)d_in[1];
    const float* W   = (const float*)d_in[2];
    const float* w2  = (const float*)d_in[3];
    float* out = (float*)d_out;

    _Float16* whT = (_Float16*)d_ws;                                  // 2 MiB
    float* s1 = (float*)((char*)d_ws + (size_t)B_ * FOUT * N_ * 2);   // 64 KiB
    float* s2 = s1 + (size_t)B_ * N_;                                 // 64 KiB

    k1_wh<<<(B_ * N_) / 32, 256, 0, stream>>>(x, W, w2, whT, s1, s2);
    k2_attn<<<(B_ * N_) / 16, 256, 0, stream>>>(adj, whT, s1, s2, out);
}